// Round 3
// baseline (5416.694 us; speedup 1.0000x reference)
//
#include <hip/hip_runtime.h>

#define NLAYER 6
#define NB     128     // batch
#define NT     512     // seq len
#define DIN    128     // layer-0 input size
#define NH     256     // hidden
#define NGRP   2       // batch groups
#define BSZ    64      // batch per group
#define NSLC   16      // hidden-slices per layer
#define HS     16      // hidden per slice  -> 64 gate rows per block
#define NBLK   (NLAYER*NSLC*NGRP)     // 192 blocks, <=256 CUs, all co-resident
#define SLOT_U64 (NB*NH/4)            // ring slot in u64 units (4 bf16 each) = 8192
#define RF_INTS  (NLAYER*NGRP*NT)     // read-token counters (back-pressure, only if Wv<NT)
#define RF_BYTES (RF_INTS*4)

typedef __attribute__((ext_vector_type(8))) short short8;
typedef __attribute__((ext_vector_type(4))) float f32x4;

__device__ __forceinline__ unsigned f2bf2(float lo, float hi){
  unsigned a = __float_as_uint(lo), b = __float_as_uint(hi);
  a = (a + 0x7fffu + ((a>>16)&1u)) >> 16;   // RNE bf16
  b = (b + 0x7fffu + ((b>>16)&1u)) >> 16;
  return a | (b<<16);
}
__device__ __forceinline__ unsigned long long f2bf4(float a, float b, float c, float d){
  return (unsigned long long)f2bf2(a,b) | ((unsigned long long)f2bf2(c,d) << 32);
}
__device__ __forceinline__ uint4 ld8f_bf(const float* p){
  f32x4 a = *(const f32x4*)p;
  f32x4 b = *(const f32x4*)(p+4);
  uint4 r;
  r.x = f2bf2(a[0],a[1]); r.y = f2bf2(a[2],a[3]);
  r.z = f2bf2(b[0],b[1]); r.w = f2bf2(b[2],b[3]);
  return r;
}

__device__ __forceinline__ float sigmf(float v){ return 1.0f/(1.0f + __expf(-v)); }
__device__ __forceinline__ float tanhfast(float v){
  v = fminf(fmaxf(v, -15.0f), 15.0f);
  float e = __expf(2.0f*v);
  return (e - 1.0f)/(e + 1.0f);
}

// All cross-block traffic: RELAXED agent-scope atomics (sc1 device-coherent ops,
// no cache-maintenance). Ordering: producer drains vmcnt(0) + barrier before the
// tag store; single coherence point (L3) => real-time order suffices.
__device__ __forceinline__ int ld_flag(int* p){
  return __hip_atomic_load(p, __ATOMIC_RELAXED, __HIP_MEMORY_SCOPE_AGENT);
}
__device__ __forceinline__ void st_flag(int* p, int v){
  __hip_atomic_store(p, v, __ATOMIC_RELAXED, __HIP_MEMORY_SCOPE_AGENT);
}
__device__ __forceinline__ void bump(int* p){
  __hip_atomic_fetch_add(p, 1, __ATOMIC_RELAXED, __HIP_MEMORY_SCOPE_AGENT);
}
__device__ __forceinline__ void waitge(int* p, int v){
  int guard = 0;
  while (ld_flag(p) < v){
    __builtin_amdgcn_s_sleep(1);
    if (++guard > (1<<21)) break;   // failsafe only
  }
}
// whole-wave poll: lanes 0..15 poll 16 slice tags for value > thr
__device__ __forceinline__ void wave_poll16(int* tp, int thr, int lane){
  int guard = 0;
  for (;;){
    int v = (lane < 16) ? ld_flag(tp + lane) : 0x7fffffff;
    unsigned long long m = __ballot(v > thr);
    if (m == ~0ull) break;
    __builtin_amdgcn_s_sleep(1);
    if (++guard > (1<<21)) break;   // failsafe only
  }
}
__device__ __forceinline__ unsigned long long ring_ld(const unsigned long long* p){
  return __hip_atomic_load(p, __ATOMIC_RELAXED, __HIP_MEMORY_SCOPE_AGENT);
}
__device__ __forceinline__ void ring_st(unsigned long long* p, unsigned long long v){
  __hip_atomic_store(p, v, __ATOMIC_RELAXED, __HIP_MEMORY_SCOPE_AGENT);
}

// 192 blocks x 256 threads. Block (l, s, g): layer l, hidden slice s (16 h), batch group g.
// Weights (w_ih||w_hh slice, bf16, MFMA-A-swizzled) stationary in LDS.
// K-loop split: x-part MFMAs run BEFORE the own-layer h_{t-1} wait (off critical path).
__global__ __launch_bounds__(256, 1)
void lstm_pipe(const float* __restrict__ x,   const float* __restrict__ h0,
               const float* __restrict__ c0,  const float* __restrict__ wih0,
               const float* __restrict__ wih, const float* __restrict__ whh,
               const float* __restrict__ bih, const float* __restrict__ bhh,
               float* __restrict__ out, int* __restrict__ rf, int* __restrict__ tags,
               unsigned long long* __restrict__ ring, int Wv)
{
  __shared__ __align__(16) unsigned char s_w[65536];   // A tiles: [4 gates][KIT][64 lanes * 16B]
  __shared__ __align__(16) unsigned char s_b[66560];   // B buf: [64 batch rows][(Ktot+8) bf16]

  const int tid  = threadIdx.x;
  const int bid  = blockIdx.x;
  const int l    = bid >> 5;          // 32 blocks per layer
  const int s    = (bid >> 1) & 15;
  const int g    = bid & 1;

  const int Kin  = (l == 0) ? DIN : NH;
  const int Ktot = Kin + NH;          // 384 or 512
  const int KIT  = Ktot >> 5;         // 12 or 16 k-iterations of 32
  const int NK1  = Kin >> 5;          // x-part k-iterations (4 or 8)
  const int BPITCH = (Ktot + 8) * 2;  // bytes per B row, 16B-aligned

  const int lane = tid & 63;
  const int wv   = tid >> 6;          // wave = N-tile (batch block of 16)
  const int quad = lane >> 4;
  const int l15  = lane & 15;

  int* Rf     = rf + (l*NGRP + g)*NT;
  int* RfPrev = rf + ((l > 0 ? l-1 : 0)*NGRP + g)*NT;
  int* tagOwn  = tags + ((l*NGRP + g)*Wv)*NSLC;
  int* tagPrev = tags + (((l > 0 ? l-1 : 0)*NGRP + g)*Wv)*NSLC;

  // ---- one-time: stage weight slice into LDS, pre-swizzled as MFMA A fragments ----
  for (int idx = tid; idx < 4*KIT*64; idx += 256){
    int lc   = idx & 63;
    int t2   = idx >> 6;
    int kt   = t2 % KIT;
    int q    = t2 / KIT;                       // gate 0..3 (i,f,g,o)
    int grow = q*NH + s*HS + (lc & 15);        // global 4H row
    int k0   = kt*32 + (lc >> 4)*8;
    const float* src;
    if (k0 < Kin){
      src = (l == 0) ? (wih0 + (size_t)grow*DIN + k0)
                     : (wih + (size_t)(l-1)*(4*NH*NH) + (size_t)grow*NH + k0);
    } else {
      src = whh + (size_t)l*(4*NH*NH) + (size_t)grow*NH + (k0 - Kin);
    }
    *(uint4*)(s_w + (q*KIT + kt)*1024 + lc*16) = ld8f_bf(src);
  }

  // ---- per-lane constants ----
  const int brow = wv*16 + l15;      // batch row within group [0,64)
  const int bloc = g*BSZ + brow;     // global batch [0,128)
  const int jcol = s*HS + quad*4;    // first of this lane's 4 hidden cols

  f32x4 bsv[4];
  #pragma unroll
  for (int q = 0; q < 4; ++q){
    f32x4 a = *(const f32x4*)(bih + (size_t)l*4*NH + q*NH + jcol);
    f32x4 b = *(const f32x4*)(bhh + (size_t)l*4*NH + q*NH + jcol);
    bsv[q] = a + b;
  }
  float cc[4];
  {
    f32x4 cv = *(const f32x4*)(c0 + ((size_t)l*NB + bloc)*NH + jcol);
    cc[0]=cv[0]; cc[1]=cv[1]; cc[2]=cv[2]; cc[3]=cv[3];
  }

  const int Wm    = Wv - 1;          // Wv is power of two
  const int KinC  = Kin >> 2;        // u64 chunks of x-part per row (32 or 64)
  const int kshift= (l == 0) ? 5 : 6;
  const int xchunks = 64*KinC;       // 2048 or 4096
  const int nRead = (l < NLAYER-1) ? 2*NSLC : NSLC;

  const unsigned long long* ringPrev = ring + (size_t)(l > 0 ? l-1 : 0)*Wv*SLOT_U64;
  unsigned long long*       ringOwn  = ring + (size_t)l*Wv*SLOT_U64;

  const unsigned char* bptr = s_b + brow*BPITCH + quad*16;
  const unsigned char* aptr = s_w + lane*16;

  for (int t = 0; t < NT; ++t){
    // ---- wait for below-layer output at t (usually already there: pipeline skew) ----
    if (wv == 0 && l > 0) wave_poll16(tagPrev + (t & Wm)*NSLC, t, lane);
    if (tid == 192 && Wv < NT && t >= Wv) waitge(Rf + (t - Wv), nRead);  // slot free
    __syncthreads();                                                     // B1

    // ---- stage x-part of B (x_t or below-layer h) as bf16 rows ----
    for (int idx = tid; idx < xchunks; idx += 256){
      int row = idx >> kshift;
      int c   = idx & (KinC - 1);
      unsigned long long v;
      if (l == 0){
        const float* px = x + (size_t)(g*BSZ + row)*(NT*DIN) + (size_t)t*DIN + c*4;
        f32x4 a = *(const f32x4*)px;
        v = f2bf4(a[0],a[1],a[2],a[3]);
      } else {
        v = ring_ld(ringPrev + (size_t)(t & Wm)*SLOT_U64 + (size_t)(g*BSZ + row)*64 + c);
      }
      *(unsigned long long*)(s_b + row*BPITCH + c*8) = v;
    }
    __syncthreads();                                                     // B2
    if (tid == 64 && Wv < NT && l > 0) bump(RfPrev + t);                 // read-token

    // ---- phase-1 MFMAs (x-part, independent of h_{t-1}) ----
    f32x4 acc0 = {0,0,0,0}, acc1 = {0,0,0,0}, acc2 = {0,0,0,0}, acc3 = {0,0,0,0};
    {
      short8 bf = *(const short8*)(bptr);
      short8 a0 = *(const short8*)(aptr + (0*KIT)*1024);
      short8 a1 = *(const short8*)(aptr + (1*KIT)*1024);
      short8 a2 = *(const short8*)(aptr + (2*KIT)*1024);
      short8 a3 = *(const short8*)(aptr + (3*KIT)*1024);
      for (int kt = 0; kt < NK1-1; ++kt){
        short8 bfn = *(const short8*)(bptr + (kt+1)*64);
        short8 a0n = *(const short8*)(aptr + (0*KIT + kt+1)*1024);
        short8 a1n = *(const short8*)(aptr + (1*KIT + kt+1)*1024);
        short8 a2n = *(const short8*)(aptr + (2*KIT + kt+1)*1024);
        short8 a3n = *(const short8*)(aptr + (3*KIT + kt+1)*1024);
        acc0 = __builtin_amdgcn_mfma_f32_16x16x32_bf16(a0, bf, acc0, 0, 0, 0);
        acc1 = __builtin_amdgcn_mfma_f32_16x16x32_bf16(a1, bf, acc1, 0, 0, 0);
        acc2 = __builtin_amdgcn_mfma_f32_16x16x32_bf16(a2, bf, acc2, 0, 0, 0);
        acc3 = __builtin_amdgcn_mfma_f32_16x16x32_bf16(a3, bf, acc3, 0, 0, 0);
        bf = bfn; a0 = a0n; a1 = a1n; a2 = a2n; a3 = a3n;
      }
      acc0 = __builtin_amdgcn_mfma_f32_16x16x32_bf16(a0, bf, acc0, 0, 0, 0);
      acc1 = __builtin_amdgcn_mfma_f32_16x16x32_bf16(a1, bf, acc1, 0, 0, 0);
      acc2 = __builtin_amdgcn_mfma_f32_16x16x32_bf16(a2, bf, acc2, 0, 0, 0);
      acc3 = __builtin_amdgcn_mfma_f32_16x16x32_bf16(a3, bf, acc3, 0, 0, 0);
    }

    // ---- critical wait: own-layer h_{t-1} tags ----
    if (wv == 0 && t > 0) wave_poll16(tagOwn + ((t-1) & Wm)*NSLC, t-1, lane);
    __syncthreads();                                                     // B3

    // ---- stage h-part of B ----
    for (int idx = tid; idx < 4096; idx += 256){
      int row = idx >> 6;
      int c   = idx & 63;
      unsigned long long v;
      if (t == 0){
        const float* ph = h0 + ((size_t)l*NB + g*BSZ + row)*NH + c*4;
        f32x4 a = *(const f32x4*)ph;
        v = f2bf4(a[0],a[1],a[2],a[3]);
      } else {
        v = ring_ld(ringOwn + (size_t)((t-1) & Wm)*SLOT_U64 + (size_t)(g*BSZ + row)*64 + c);
      }
      *(unsigned long long*)(s_b + row*BPITCH + (KinC + c)*8) = v;
    }
    __syncthreads();                                                     // B4
    if (tid == 0 && Wv < NT && t > 0) bump(Rf + (t-1));                  // read-token

    // ---- phase-2 MFMAs (h-part) ----
    {
      short8 bf = *(const short8*)(bptr + NK1*64);
      short8 a0 = *(const short8*)(aptr + (0*KIT + NK1)*1024);
      short8 a1 = *(const short8*)(aptr + (1*KIT + NK1)*1024);
      short8 a2 = *(const short8*)(aptr + (2*KIT + NK1)*1024);
      short8 a3 = *(const short8*)(aptr + (3*KIT + NK1)*1024);
      for (int kt = NK1; kt < KIT-1; ++kt){
        short8 bfn = *(const short8*)(bptr + (kt+1)*64);
        short8 a0n = *(const short8*)(aptr + (0*KIT + kt+1)*1024);
        short8 a1n = *(const short8*)(aptr + (1*KIT + kt+1)*1024);
        short8 a2n = *(const short8*)(aptr + (2*KIT + kt+1)*1024);
        short8 a3n = *(const short8*)(aptr + (3*KIT + kt+1)*1024);
        acc0 = __builtin_amdgcn_mfma_f32_16x16x32_bf16(a0, bf, acc0, 0, 0, 0);
        acc1 = __builtin_amdgcn_mfma_f32_16x16x32_bf16(a1, bf, acc1, 0, 0, 0);
        acc2 = __builtin_amdgcn_mfma_f32_16x16x32_bf16(a2, bf, acc2, 0, 0, 0);
        acc3 = __builtin_amdgcn_mfma_f32_16x16x32_bf16(a3, bf, acc3, 0, 0, 0);
        bf = bfn; a0 = a0n; a1 = a1n; a2 = a2n; a3 = a3n;
      }
      acc0 = __builtin_amdgcn_mfma_f32_16x16x32_bf16(a0, bf, acc0, 0, 0, 0);
      acc1 = __builtin_amdgcn_mfma_f32_16x16x32_bf16(a1, bf, acc1, 0, 0, 0);
      acc2 = __builtin_amdgcn_mfma_f32_16x16x32_bf16(a2, bf, acc2, 0, 0, 0);
      acc3 = __builtin_amdgcn_mfma_f32_16x16x32_bf16(a3, bf, acc3, 0, 0, 0);
    }

    // ---- fused gate nonlinearities + state update ----
    float hv[4];
    #pragma unroll
    for (int r = 0; r < 4; ++r){
      float ig = sigmf(acc0[r] + bsv[0][r]);
      float fg = sigmf(acc1[r] + bsv[1][r]);
      float gv = tanhfast(acc2[r] + bsv[2][r]);
      float og = sigmf(acc3[r] + bsv[3][r]);
      float cn = fg*cc[r] + ig*gv;
      cc[r] = cn;
      hv[r] = og * tanhfast(cn);
    }

    // publish h_t slice (8B device-coherent store), drain, then per-slice tag
    ring_st(ringOwn + (size_t)(t & Wm)*SLOT_U64 + (size_t)bloc*64 + s*4 + quad,
            f2bf4(hv[0], hv[1], hv[2], hv[3]));
    if (t == NT-1){
      f32x4 ov; ov[0]=hv[0]; ov[1]=hv[1]; ov[2]=hv[2]; ov[3]=hv[3];
      *(f32x4*)(out + ((size_t)l*NB + bloc)*NH + jcol) = ov;
    }
    asm volatile("s_waitcnt vmcnt(0)" ::: "memory");   // h stores ack'd at L3
    __syncthreads();                                                     // B5
    if (tid == 0) st_flag(tagOwn + (t & Wm)*NSLC + s, t+1);
  }
}

extern "C" void kernel_launch(void* const* d_in, const int* in_sizes, int n_in,
                              void* d_out, int out_size, void* d_ws, size_t ws_size,
                              hipStream_t stream)
{
  (void)in_sizes; (void)n_in; (void)out_size;
  const float* x    = (const float*)d_in[0];
  const float* h0   = (const float*)d_in[1];
  const float* c0   = (const float*)d_in[2];
  const float* wih0 = (const float*)d_in[3];
  const float* wih  = (const float*)d_in[4];
  const float* whh  = (const float*)d_in[5];
  const float* bih  = (const float*)d_in[6];
  const float* bhh  = (const float*)d_in[7];

  // prefer full-depth ring (no back-pressure machinery at all)
  int Wv = NT;
  for (;;){
    size_t tagB  = (size_t)NLAYER*NGRP*Wv*NSLC*4;
    size_t ringB = (size_t)NLAYER*Wv*SLOT_U64*8;
    if ((size_t)RF_BYTES + tagB + ringB <= ws_size || Wv <= 2) break;
    Wv >>= 1;
  }
  size_t tagB = (size_t)NLAYER*NGRP*Wv*NSLC*4;

  int* rf   = (int*)d_ws;
  int* tags = (int*)((char*)d_ws + RF_BYTES);
  unsigned long long* ring = (unsigned long long*)((char*)d_ws + RF_BYTES + tagB);

  (void)hipMemsetAsync(d_ws, 0, RF_BYTES + tagB, stream);
  hipLaunchKernelGGL(lstm_pipe, dim3(NBLK), dim3(256), 0, stream,
                     x, h0, c0, wih0, wih, whh, bih, bhh,
                     (float*)d_out, rf, tags, ring, Wv);
}

// Round 4
// 3111.166 us; speedup vs baseline: 1.7410x; 1.7410x over previous
//
#include <hip/hip_runtime.h>

#define NLAYER 6
#define NB     128     // batch
#define NT     512     // seq len
#define DIN    128     // layer-0 input size
#define NH     256     // hidden
#define NBLK   192     // 6 layers x 16 slices x 2 batch-groups, all co-resident
#define SLOT_U64 (NB*NH/4)            // ring slot in u64 units (4 bf16 each) = 8192

typedef __attribute__((ext_vector_type(8))) short short8;
typedef __attribute__((ext_vector_type(4))) float f32x4;

__device__ __forceinline__ unsigned f2bf2(float lo, float hi){
  unsigned a = __float_as_uint(lo), b = __float_as_uint(hi);
  a = (a + 0x7fffu + ((a>>16)&1u)) >> 16;   // RNE bf16
  b = (b + 0x7fffu + ((b>>16)&1u)) >> 16;
  return a | (b<<16);
}
__device__ __forceinline__ unsigned long long f2bf4(float a, float b, float c, float d){
  return (unsigned long long)f2bf2(a,b) | ((unsigned long long)f2bf2(c,d) << 32);
}
__device__ __forceinline__ short8 pack16(unsigned long long lo, unsigned long long hi){
  union { unsigned long long u[2]; short8 v; } w; w.u[0]=lo; w.u[1]=hi; return w.v;
}
// 8 consecutive fp32 -> one MFMA bf16 fragment (4 VGPRs)
__device__ __forceinline__ short8 ld8f_frag(const float* p){
  f32x4 a = *(const f32x4*)p;
  f32x4 b = *(const f32x4*)(p+4);
  return pack16(f2bf4(a[0],a[1],a[2],a[3]), f2bf4(b[0],b[1],b[2],b[3]));
}

__device__ __forceinline__ float sigmf(float v){ return 1.0f/(1.0f + __expf(-v)); }
__device__ __forceinline__ float tanhfast(float v){
  v = fminf(fmaxf(v, -15.0f), 15.0f);
  float e = __expf(2.0f*v);
  return (e - 1.0f)/(e + 1.0f);
}

// Relaxed agent-scope atomics: device-coherent at the fabric, no cache maintenance.
// Producer order: data stores -> s_waitcnt vmcnt(0) -> tag store. Single coherence
// point => a consumer that observes the tag observes the data with later loads.
__device__ __forceinline__ int ld_flag(int* p){
  return __hip_atomic_load(p, __ATOMIC_RELAXED, __HIP_MEMORY_SCOPE_AGENT);
}
__device__ __forceinline__ void st_flag(int* p, int v){
  __hip_atomic_store(p, v, __ATOMIC_RELAXED, __HIP_MEMORY_SCOPE_AGENT);
}
__device__ __forceinline__ unsigned long long ring_ld(const unsigned long long* p){
  return __hip_atomic_load(p, __ATOMIC_RELAXED, __HIP_MEMORY_SCOPE_AGENT);
}
__device__ __forceinline__ void ring_st(unsigned long long* p, unsigned long long v){
  __hip_atomic_store(p, v, __ATOMIC_RELAXED, __HIP_MEMORY_SCOPE_AGENT);
}
// whole-wave poll: lanes 0..15 poll 16 consecutive tags (one 64B line) for >= val
__device__ __forceinline__ void poll_ge16(int* tp, int val, int lane){
  int guard = 0;
  for (;;){
    int v = (lane < 16) ? ld_flag(tp + lane) : 0x7fffffff;
    if (__ballot(v >= val) == ~0ull) break;
    __builtin_amdgcn_s_sleep(1);
    if (++guard > (1<<22)) break;   // failsafe only
  }
}

// Wave-dataflow LSTM: no __syncthreads, no LDS. Each wave owns a 16h x 16b tile:
// A (weights) stationary in VGPRs, B (x||h) loaded straight into MFMA fragments
// from the ring, h published per-wave with per-wave tags.
template<int NKX, int KIT>
__device__ __forceinline__ void lstm_run(
    const float* __restrict__ x,  const float* __restrict__ h0,
    const float* __restrict__ c0, const float* __restrict__ wx,
    const float* __restrict__ wh, const float* __restrict__ bi,
    const float* __restrict__ bh, float* __restrict__ out,
    int* __restrict__ tags, int* __restrict__ acks,
    unsigned long long* __restrict__ ring,
    int Wv, int l, int s, int g, int wv, int lane)
{
  constexpr int NKH = KIT - NKX;    // h-part k-iterations (8)
  constexpr int KX  = NKX*32;       // input width (128 or 256)
  const int l15  = lane & 15;
  const int quad = lane >> 4;
  const int bloc = g*64 + wv*16 + l15;   // this lane's batch row
  const int jcol = s*16 + quad*4;        // this lane's first hidden col
  const int Wm   = Wv - 1;

  // ---- A fragments: stationary in VGPRs (4 gates x KIT kts x 4 VGPR) ----
  short8 A[4][KIT];
  #pragma unroll
  for (int q = 0; q < 4; ++q){
    const float* wrow_x = wx + (size_t)(q*NH + s*16 + l15)*KX;
    const float* wrow_h = wh + (size_t)(q*NH + s*16 + l15)*NH;
    #pragma unroll
    for (int kt = 0; kt < KIT; ++kt){
      int k0 = kt*32 + quad*8;
      A[q][kt] = (k0 < KX) ? ld8f_frag(wrow_x + k0)
                           : ld8f_frag(wrow_h + (k0 - KX));
    }
  }

  f32x4 bsv[4];
  #pragma unroll
  for (int q = 0; q < 4; ++q){
    f32x4 a = *(const f32x4*)(bi + q*NH + jcol);
    f32x4 b = *(const f32x4*)(bh + q*NH + jcol);
    bsv[q] = a + b;
  }
  float cc[4];
  {
    f32x4 cv = *(const f32x4*)(c0 + ((size_t)l*NB + bloc)*NH + jcol);
    cc[0]=cv[0]; cc[1]=cv[1]; cc[2]=cv[2]; cc[3]=cv[3];
  }

  int* tagOwn  = tags + ((l*2 + g)*Wv)*64;                     // [slot][wv][s]
  int* tagPrev = tags + (((l > 0 ? l-1 : 0)*2 + g)*Wv)*64;
  int* ackOwn  = acks + ((l*2 + g)*Wv)*64;
  int* ackPrev = acks + (((l > 0 ? l-1 : 0)*2 + g)*Wv)*64;
  const unsigned long long* ringPrev = ring + (size_t)(l > 0 ? l-1 : 0)*Wv*SLOT_U64;
  unsigned long long*       ringOwn  = ring + (size_t)l*Wv*SLOT_U64;
  const bool lastL = (l == NLAYER-1);
  const bool bp    = (Wv < NT);     // back-pressure machinery active?

  for (int t = 0; t < NT; ++t){
    const int slot  = t & Wm;
    const int pslot = (t-1) & Wm;

    // WAR guard (only if ring wraps): next layer must have consumed slot t-Wv
    if (bp && !lastL && t >= Wv) poll_ge16(ackOwn + slot*64 + wv*16, t - Wv + 1, lane);

    // ---- x-part B fragments ----
    short8 Bx[NKX];
    if constexpr (NKX == 4){
      const float* px = x + ((size_t)bloc*NT + t)*DIN + quad*8;   // plain L2-cached loads
      #pragma unroll
      for (int k = 0; k < NKX; ++k) Bx[k] = ld8f_frag(px + k*32);
    } else {
      poll_ge16(tagPrev + slot*64 + wv*16, t+1, lane);
      asm volatile("" ::: "memory");
      const unsigned long long* pb = ringPrev + (size_t)slot*SLOT_U64 + (size_t)bloc*64 + quad*2;
      #pragma unroll
      for (int k = 0; k < NKX; ++k) Bx[k] = pack16(ring_ld(pb + k*8), ring_ld(pb + k*8 + 1));
    }

    // ---- own-layer h fragments (the critical wait) ----
    short8 Bh[NKH];
    if (t == 0){
      const float* ph = h0 + ((size_t)l*NB + bloc)*NH + quad*8;
      #pragma unroll
      for (int k = 0; k < NKH; ++k) Bh[k] = ld8f_frag(ph + k*32);
    } else {
      poll_ge16(tagOwn + pslot*64 + wv*16, t, lane);
      asm volatile("" ::: "memory");
      const unsigned long long* pb = ringOwn + (size_t)pslot*SLOT_U64 + (size_t)bloc*64 + quad*2;
      #pragma unroll
      for (int k = 0; k < NKH; ++k) Bh[k] = pack16(ring_ld(pb + k*8), ring_ld(pb + k*8 + 1));
    }

    // ---- MFMAs: x-part first (overlaps h-load latency), then h-part ----
    f32x4 a0 = {0,0,0,0}, a1 = {0,0,0,0}, a2 = {0,0,0,0}, a3 = {0,0,0,0};
    #pragma unroll
    for (int k = 0; k < NKX; ++k){
      a0 = __builtin_amdgcn_mfma_f32_16x16x32_bf16(A[0][k], Bx[k], a0, 0, 0, 0);
      a1 = __builtin_amdgcn_mfma_f32_16x16x32_bf16(A[1][k], Bx[k], a1, 0, 0, 0);
      a2 = __builtin_amdgcn_mfma_f32_16x16x32_bf16(A[2][k], Bx[k], a2, 0, 0, 0);
      a3 = __builtin_amdgcn_mfma_f32_16x16x32_bf16(A[3][k], Bx[k], a3, 0, 0, 0);
    }
    if constexpr (NKX == 8){
      // ack prev-layer slot consumed (x loads complete: consumed by MFMAs above)
      if (bp){
        asm volatile("s_waitcnt vmcnt(0)" ::: "memory");
        if (lane == 0) st_flag(ackPrev + slot*64 + wv*16 + s, t+1);
      }
    }
    #pragma unroll
    for (int k = 0; k < NKH; ++k){
      a0 = __builtin_amdgcn_mfma_f32_16x16x32_bf16(A[0][NKX+k], Bh[k], a0, 0, 0, 0);
      a1 = __builtin_amdgcn_mfma_f32_16x16x32_bf16(A[1][NKX+k], Bh[k], a1, 0, 0, 0);
      a2 = __builtin_amdgcn_mfma_f32_16x16x32_bf16(A[2][NKX+k], Bh[k], a2, 0, 0, 0);
      a3 = __builtin_amdgcn_mfma_f32_16x16x32_bf16(A[3][NKX+k], Bh[k], a3, 0, 0, 0);
    }

    // ---- fused gate nonlinearities + state update ----
    float hv[4];
    #pragma unroll
    for (int r = 0; r < 4; ++r){
      float ig = sigmf(a0[r] + bsv[0][r]);
      float fg = sigmf(a1[r] + bsv[1][r]);
      float gv = tanhfast(a2[r] + bsv[2][r]);
      float og = sigmf(a3[r] + bsv[3][r]);
      float cn = fg*cc[r] + ig*gv;
      cc[r] = cn;
      hv[r] = og * tanhfast(cn);
    }

    // ---- publish: 8B device-coherent store, drain, per-wave tag ----
    ring_st(ringOwn + (size_t)slot*SLOT_U64 + (size_t)bloc*64 + s*4 + quad,
            f2bf4(hv[0], hv[1], hv[2], hv[3]));
    if (t == NT-1){
      f32x4 ov; ov[0]=hv[0]; ov[1]=hv[1]; ov[2]=hv[2]; ov[3]=hv[3];
      *(f32x4*)(out + ((size_t)l*NB + bloc)*NH + jcol) = ov;
    }
    asm volatile("s_waitcnt vmcnt(0)" ::: "memory");
    if (lane == 0) st_flag(tagOwn + slot*64 + wv*16 + s, t+1);
  }
}

__global__ __launch_bounds__(256, 1)
void lstm_pipe(const float* __restrict__ x,   const float* __restrict__ h0,
               const float* __restrict__ c0,  const float* __restrict__ wih0,
               const float* __restrict__ wih, const float* __restrict__ whh,
               const float* __restrict__ bih, const float* __restrict__ bhh,
               float* __restrict__ out, int* __restrict__ tags, int* __restrict__ acks,
               unsigned long long* __restrict__ ring, int Wv)
{
  const int tid  = threadIdx.x;
  const int bid  = blockIdx.x;
  const int l    = bid >> 5;          // 32 blocks per layer
  const int s    = (bid >> 1) & 15;
  const int g    = bid & 1;
  const int lane = tid & 63;
  const int wv   = tid >> 6;

  if (l == 0)
    lstm_run<4,12>(x, h0, c0, wih0, whh, bih, bhh,
                   out, tags, acks, ring, Wv, 0, s, g, wv, lane);
  else
    lstm_run<8,16>(x, h0, c0,
                   wih + (size_t)(l-1)*(4*NH*NH),
                   whh + (size_t)l*(4*NH*NH),
                   bih + (size_t)l*(4*NH),
                   bhh + (size_t)l*(4*NH),
                   out, tags, acks, ring, Wv, l, s, g, wv, lane);
}

extern "C" void kernel_launch(void* const* d_in, const int* in_sizes, int n_in,
                              void* d_out, int out_size, void* d_ws, size_t ws_size,
                              hipStream_t stream)
{
  (void)in_sizes; (void)n_in; (void)out_size;
  const float* x    = (const float*)d_in[0];
  const float* h0   = (const float*)d_in[1];
  const float* c0   = (const float*)d_in[2];
  const float* wih0 = (const float*)d_in[3];
  const float* wih  = (const float*)d_in[4];
  const float* whh  = (const float*)d_in[5];
  const float* bih  = (const float*)d_in[6];
  const float* bhh  = (const float*)d_in[7];

  // full-depth ring preferred (no WAR, no back-pressure); shrink if ws small
  int Wv = NT;
  size_t tagB;
  for (;;){
    tagB = (size_t)NLAYER*2*Wv*64*4;
    size_t ringB = (size_t)NLAYER*Wv*SLOT_U64*8;
    if (2*tagB + ringB <= ws_size || Wv <= 4) break;
    Wv >>= 1;
  }

  int* tags = (int*)d_ws;
  int* acks = (int*)((char*)d_ws + tagB);
  unsigned long long* ring = (unsigned long long*)((char*)d_ws + 2*tagB);

  (void)hipMemsetAsync(d_ws, 0, 2*tagB, stream);
  hipLaunchKernelGGL(lstm_pipe, dim3(NBLK), dim3(256), 0, stream,
                     x, h0, c0, wih0, wih, whh, bih, bhh,
                     (float*)d_out, tags, acks, ring, Wv);
}